// Round 16
// baseline (328.553 us; speedup 1.0000x reference)
//
#include <hip/hip_runtime.h>
#include <hip/hip_bf16.h>

// GravNet: 32 graphs x 256 nodes, IN=64, HID=256, OUT=32, K=20, SPACE=3, PROP=2
// 2-launch pipeline, ZERO fences (only cross-kernel plain-store handoffs):
//  K2 (384 blk x 512 thr): blocks 0..255: BM=32 — in-block sh1 + kNN own 32 rows +
//     gemm1 (A=X split->LDS swz; B=Wo1 split in regs) + h1 planes + complete s2/hp2.
//     blocks 256..383: rider = Wo2->Wt2 split.                      [R14-verified]
//  K3 (32 blk x 1024 thr): ONE BLOCK PER GRAPH — knn2 (16 waves x 4 rows x 4 passes),
//     gemm2 K=256 in 8 row-chunks of 32 (CT LDS reused), s3/hp3 accumulated in LDS,
//     h2c row kept in LDS, then knn3 + final 258->32 matvec inline. No k4, no fence,
//     no global round-trip for s3/hp3/h2c. [R16: replaces R15's fence fold that cost
//     +20us in per-block L2 writebacks.]
// GEMM x-part: split-bf16 MFMA (hi/lo, 3 products) == fp32 precision.

#define NGRAPH 32
#define GN 256
#define NTOT (NGRAPH*GN) // 8192
#define KNN 20
#define CTS 257          // CT leading dim (floats): 257%32==1 -> conflict-free columns

typedef __attribute__((ext_vector_type(8))) short bf16x8;
typedef __attribute__((ext_vector_type(4))) float f32x4;

__device__ __forceinline__ ushort f2bf(float x) {
    union { float f; unsigned u; } a; a.f = x;
    unsigned r = a.u + 0x7FFFu + ((a.u >> 16) & 1u);   // RNE
    return (ushort)(r >> 16);
}
__device__ __forceinline__ float bf2f(ushort h) {
    union { unsigned u; float f; } b; b.u = ((unsigned)h) << 16;
    return b.f;
}
__device__ __forceinline__ bf16x8 ld8(const ushort* p) {
    return *reinterpret_cast<const bf16x8*>(p);
}
__device__ __forceinline__ unsigned pack2(ushort a, ushort b) {
    return (unsigned)a | ((unsigned)b << 16);
}

// ---- DPP primitives (VALU-only) ----
#define DPP_MIN(v, ctrl, rmask) { \
    unsigned _t = (unsigned)__builtin_amdgcn_update_dpp((int)(v), (int)(v), ctrl, rmask, 0xf, false); \
    (v) = _t < (v) ? _t : (v); }
#define DPP_ADD(v, ctrl, rmask) { \
    float _t = __int_as_float(__builtin_amdgcn_update_dpp(0, __float_as_int(v), ctrl, rmask, 0xf, true)); \
    (v) += _t; }
__device__ __forceinline__ unsigned wave_min_u32(unsigned v) {
    DPP_MIN(v, 0x111, 0xf)
    DPP_MIN(v, 0x112, 0xf)
    DPP_MIN(v, 0x114, 0xf)
    DPP_MIN(v, 0x118, 0xf)
    DPP_MIN(v, 0x142, 0xa)
    DPP_MIN(v, 0x143, 0xc)
    return (unsigned)__builtin_amdgcn_readlane((int)v, 63);
}
__device__ __forceinline__ float wave_sum_f32(float v) {
    DPP_ADD(v, 0x111, 0xf)
    DPP_ADD(v, 0x112, 0xf)
    DPP_ADD(v, 0x114, 0xf)
    DPP_ADD(v, 0x118, 0xf)
    DPP_ADD(v, 0x142, 0xa)
    DPP_ADD(v, 0x143, 0xc)
    return __int_as_float(__builtin_amdgcn_readlane(__float_as_int(v), 63));
}

// ---- serial kNN extraction (K3 tail only) ----
__device__ __forceinline__ void knn_extract(
    unsigned ua, unsigned ub, unsigned uc, unsigned ud,
    float2 hA, float2 hB, float2 hC, float2 hD,
    int lane, float& out0, float& out1)
{
    float acc0 = 0.f, acc1 = 0.f;
#pragma unroll 1
    for (int it = 0; it < KNN; ++it) {
        unsigned m1 = ua < ub ? ua : ub;
        unsigned m2 = uc < ud ? uc : ud;
        unsigned bv = m1 < m2 ? m1 : m2;
        unsigned gv = wave_min_u32(bv);
        float d2 = __uint_as_float(gv);
        float w = __expf(-10.0f * d2);
        unsigned long long mask = __ballot(bv == gv);
        int wl = __ffsll(mask) - 1;
        if (lane == wl) {
            float h0, h1;
            if (ua == gv)      { h0 = hA.x; h1 = hA.y; ua = 0xFFFFFFFFu; }
            else if (ub == gv) { h0 = hB.x; h1 = hB.y; ub = 0xFFFFFFFFu; }
            else if (uc == gv) { h0 = hC.x; h1 = hC.y; uc = 0xFFFFFFFFu; }
            else               { h0 = hD.x; h1 = hD.y; ud = 0xFFFFFFFFu; }
            acc0 = fmaf(w, h0, acc0);
            acc1 = fmaf(w, h1, acc1);
        }
    }
    out0 = wave_sum_f32(acc0);
    out1 = wave_sum_f32(acc1);
}

// ---- 4 kNN rows per wave (ILP-interleaved chains); sh5 = [256][5] LDS; out -> aggL LDS --
__device__ __forceinline__ void knn_rows4(
    const float* sh5, int srow, int orow, int lane, float* __restrict__ aggL)
{
    float sjx[4], sjy[4], sjz[4], s2j[4];
    float2 hs[4];
#pragma unroll
    for (int t = 0; t < 4; ++t) {
        int j = lane + 64 * t;
        float x = sh5[j * 5 + 0], y = sh5[j * 5 + 1], z = sh5[j * 5 + 2];
        sjx[t] = x; sjy[t] = y; sjz[t] = z;
        s2j[t] = x * x + y * y + z * z;
        hs[t] = make_float2(sh5[j * 5 + 3], sh5[j * 5 + 4]);
    }
    unsigned key[4][4];
    float acc0[4], acc1[4];
#pragma unroll
    for (int r = 0; r < 4; ++r) {
        int rl = srow + r;
        float s0 = sh5[rl * 5 + 0], s1v = sh5[rl * 5 + 1], s2v = sh5[rl * 5 + 2];
        float s2row = s0 * s0 + s1v * s1v + s2v * s2v;
#pragma unroll
        for (int t = 0; t < 4; ++t) {
            float dot = s0 * sjx[t] + s1v * sjy[t] + s2v * sjz[t];
            float d2 = s2row + s2j[t] - 2.0f * dot;
            key[r][t] = __float_as_uint(d2 > 0.f ? d2 : 0.f);
        }
        acc0[r] = 0.f; acc1[r] = 0.f;
    }
#pragma unroll 1
    for (int it = 0; it < KNN; ++it) {
        unsigned bv[4], gv[4];
#pragma unroll
        for (int r = 0; r < 4; ++r) {
            unsigned m1 = key[r][0] < key[r][1] ? key[r][0] : key[r][1];
            unsigned m2 = key[r][2] < key[r][3] ? key[r][2] : key[r][3];
            bv[r] = m1 < m2 ? m1 : m2;
            gv[r] = bv[r];
        }
#define KSTAGE(ctrl, rmask) { \
        DPP_MIN(gv[0], ctrl, rmask) DPP_MIN(gv[1], ctrl, rmask) \
        DPP_MIN(gv[2], ctrl, rmask) DPP_MIN(gv[3], ctrl, rmask) }
        KSTAGE(0x111, 0xf) KSTAGE(0x112, 0xf) KSTAGE(0x114, 0xf)
        KSTAGE(0x118, 0xf) KSTAGE(0x142, 0xa) KSTAGE(0x143, 0xc)
#undef KSTAGE
#pragma unroll
        for (int r = 0; r < 4; ++r) {
            unsigned g = (unsigned)__builtin_amdgcn_readlane((int)gv[r], 63);
            float w = __expf(-10.0f * __uint_as_float(g));
            unsigned long long mask = __ballot(bv[r] == g);
            int wl = __ffsll(mask) - 1;
            if (lane == wl) {
                float h0, h1;
                if (key[r][0] == g)      { h0 = hs[0].x; h1 = hs[0].y; key[r][0] = 0xFFFFFFFFu; }
                else if (key[r][1] == g) { h0 = hs[1].x; h1 = hs[1].y; key[r][1] = 0xFFFFFFFFu; }
                else if (key[r][2] == g) { h0 = hs[2].x; h1 = hs[2].y; key[r][2] = 0xFFFFFFFFu; }
                else                     { h0 = hs[3].x; h1 = hs[3].y; key[r][3] = 0xFFFFFFFFu; }
                acc0[r] = fmaf(w, h0, acc0[r]);
                acc1[r] = fmaf(w, h1, acc1[r]);
            }
        }
    }
#define SSTAGE(ctrl, rmask) { \
    DPP_ADD(acc0[0], ctrl, rmask) DPP_ADD(acc1[0], ctrl, rmask) \
    DPP_ADD(acc0[1], ctrl, rmask) DPP_ADD(acc1[1], ctrl, rmask) \
    DPP_ADD(acc0[2], ctrl, rmask) DPP_ADD(acc1[2], ctrl, rmask) \
    DPP_ADD(acc0[3], ctrl, rmask) DPP_ADD(acc1[3], ctrl, rmask) }
    SSTAGE(0x111, 0xf) SSTAGE(0x112, 0xf) SSTAGE(0x114, 0xf)
    SSTAGE(0x118, 0xf) SSTAGE(0x142, 0xa) SSTAGE(0x143, 0xc)
#undef SSTAGE
    if (lane == 63) {
#pragma unroll
        for (int r = 0; r < 4; ++r) {
            aggL[(orow + r) * 2 + 0] = acc0[r];
            aggL[(orow + r) * 2 + 1] = acc1[r];
        }
    }
}

// ========== K2: BM=32 — sh1 + knn1 + gemm1 (B in regs) + h1 + s2/hp2 | Wt2 rider ==========
__global__ __launch_bounds__(512) void k2_fused(
    const float* __restrict__ X,
    const float* __restrict__ Ws1, const float* __restrict__ bs1,
    const float* __restrict__ Wh1, const float* __restrict__ bh1,
    const float* __restrict__ Wo1, const float* __restrict__ bo1,
    const float* __restrict__ Ws2, const float* __restrict__ Wh2,
    const float* __restrict__ bs2, const float* __restrict__ bh2,
    const float* __restrict__ Wo2,
    ushort* __restrict__ Wt2hi, ushort* __restrict__ Wt2lo,
    ushort* __restrict__ h1hi, ushort* __restrict__ h1lo,
    float* __restrict__ s2, float* __restrict__ hp2)
{
    const int x = blockIdx.x, tid = threadIdx.x;
    if (x >= 256) {                        // ---- rider: Wo2[2+c][n] -> Wt2[n][c] hi/lo
        int t = (x - 256) * 512 + tid;     // 0..65535
        int n = t >> 8, c = t & 255;
        float v = Wo2[(size_t)(2 + c) * 256 + n];
        ushort hi = f2bf(v);
        Wt2hi[n * 256 + c] = hi;
        Wt2lo[n * 256 + c] = f2bf(v - bf2f(hi));
        return;
    }
    __shared__ float sh5[256 * 5];
    __shared__ float aggL[32 * 2];
    __shared__ ushort Ahi[32 * 64];
    __shared__ ushort Alo[32 * 64];
    __shared__ float CT[32 * CTS];
    __shared__ float part[32 * 16 * 5];    // total ~56.7 KB -> 2 blk/CU

    const int lane = tid & 63, wid = tid >> 6;
    const int g = x >> 3, m0 = x * 32, lr0 = (x & 7) * 32;

    // B fragments (Wo1) straight to REGISTERS
    bf16x8 bh[2][2], bl[2][2];   // [kof/32][ni]
    {
        int nb = wid * 32 + (lane & 15);
        int k0 = (lane >> 4) * 8;
#pragma unroll
        for (int kk = 0; kk < 2; ++kk)
#pragma unroll
            for (int ni = 0; ni < 2; ++ni) {
                union { bf16x8 v; ushort u[8]; } H, L;
#pragma unroll
                for (int j = 0; j < 8; ++j) {
                    float v = Wo1[(size_t)(2 + kk * 32 + k0 + j) * 256 + nb + ni * 16];
                    ushort hi = f2bf(v);
                    H.u[j] = hi;
                    L.u[j] = f2bf(v - bf2f(hi));
                }
                bh[kk][ni] = H.v; bl[kk][ni] = L.v;
            }
    }
    // sh1: project all 256 nodes of graph g (redundant x8 across sibling blocks)
    if (tid < 256) {
        const float* xr = X + ((size_t)g * GN + tid) * 64;
        float a0 = 0.f, a1 = 0.f, a2 = 0.f, a3 = 0.f, a4 = 0.f;
#pragma unroll 4
        for (int c0 = 0; c0 < 64; c0 += 4) {
            float4 v = *reinterpret_cast<const float4*>(&xr[c0]);
            float xv[4] = {v.x, v.y, v.z, v.w};
#pragma unroll
            for (int j = 0; j < 4; ++j) {
                int c = c0 + j;
                a0 = fmaf(xv[j], Ws1[c * 3 + 0], a0);
                a1 = fmaf(xv[j], Ws1[c * 3 + 1], a1);
                a2 = fmaf(xv[j], Ws1[c * 3 + 2], a2);
                a3 = fmaf(xv[j], Wh1[c * 2 + 0], a3);
                a4 = fmaf(xv[j], Wh1[c * 2 + 1], a4);
            }
        }
        sh5[tid * 5 + 0] = a0 + bs1[0];
        sh5[tid * 5 + 1] = a1 + bs1[1];
        sh5[tid * 5 + 2] = a2 + bs1[2];
        sh5[tid * 5 + 3] = a3 + bh1[0];
        sh5[tid * 5 + 4] = a4 + bh1[1];
    }
    // A-split: X rows m0..m0+31 -> Ahi/Alo (XOR-swizzled), 1 float4/thread
    {
        int row = tid >> 4, c4 = (tid & 15) * 4;
        float4 v = *reinterpret_cast<const float4*>(&X[(size_t)(m0 + row) * 64 + c4]);
        int idx = (row * 64 + c4) ^ ((row & 7) << 3);
        ushort4 hi, lo;
        hi.x = f2bf(v.x); lo.x = f2bf(v.x - bf2f(hi.x));
        hi.y = f2bf(v.y); lo.y = f2bf(v.y - bf2f(hi.y));
        hi.z = f2bf(v.z); lo.z = f2bf(v.z - bf2f(hi.z));
        hi.w = f2bf(v.w); lo.w = f2bf(v.w - bf2f(hi.w));
        *reinterpret_cast<ushort4*>(&Ahi[idx]) = hi;
        *reinterpret_cast<ushort4*>(&Alo[idx]) = lo;
    }
    __syncthreads();

    knn_rows4(sh5, lr0 + wid * 4, wid * 4, lane, aggL);

    // gemm1: BM=32, wave-local 32 cols, K=64; acc[2][2]
    f32x4 acc[2][2];
#pragma unroll
    for (int mi = 0; mi < 2; ++mi)
#pragma unroll
        for (int ni = 0; ni < 2; ++ni)
            acc[mi][ni] = (f32x4){0.f, 0.f, 0.f, 0.f};
#pragma unroll
    for (int kk = 0; kk < 2; ++kk) {
        int kch = kk * 32 + (lane >> 4) * 8;
        bf16x8 ah[2], al[2];
#pragma unroll
        for (int mi = 0; mi < 2; ++mi) {
            int r = mi * 16 + (lane & 15);
            int idx = (r * 64 + kch) ^ ((r & 7) << 3);
            ah[mi] = ld8(&Ahi[idx]); al[mi] = ld8(&Alo[idx]);
        }
#pragma unroll
        for (int mi = 0; mi < 2; ++mi)
#pragma unroll
            for (int ni = 0; ni < 2; ++ni) {
                acc[mi][ni] = __builtin_amdgcn_mfma_f32_16x16x32_bf16(ah[mi], bh[kk][ni], acc[mi][ni], 0, 0, 0);
                acc[mi][ni] = __builtin_amdgcn_mfma_f32_16x16x32_bf16(ah[mi], bl[kk][ni], acc[mi][ni], 0, 0, 0);
                acc[mi][ni] = __builtin_amdgcn_mfma_f32_16x16x32_bf16(al[mi], bh[kk][ni], acc[mi][ni], 0, 0, 0);
            }
    }
    __syncthreads();   // aggL complete before epilogue

    // epilogue: + agg@Wa + bias, leaky -> CT (C/D map: col=lane&15, row=(lane>>4)*4+r)
#pragma unroll
    for (int ni = 0; ni < 2; ++ni) {
        int n = wid * 32 + ni * 16 + (lane & 15);
        float w0 = Wo1[n], w1 = Wo1[256 + n], bz = bo1[n];
#pragma unroll
        for (int mi = 0; mi < 2; ++mi) {
            int mb = mi * 16 + ((lane >> 4) << 2);
#pragma unroll
            for (int r = 0; r < 4; ++r) {
                int ml = mb + r;
                float v = acc[mi][ni][r] + fmaf(aggL[ml * 2 + 0], w0, fmaf(aggL[ml * 2 + 1], w1, bz));
                CT[ml * CTS + n] = v >= 0.f ? v : 0.01f * v;
            }
        }
    }
    __syncthreads();

    // h1 planes from CT (coalesced packed stores): 512 thr x 16 cols
    {
        int row = tid >> 4, cb = (tid & 15) * 16;
        size_t m = (size_t)(m0 + row);
#pragma unroll
        for (int j = 0; j < 2; ++j) {
            int c = cb + j * 8;
            ushort hi[8], lo[8];
#pragma unroll
            for (int t = 0; t < 8; ++t) {
                float v = CT[row * CTS + c + t];
                hi[t] = f2bf(v);
                lo[t] = f2bf(v - bf2f(hi[t]));
            }
            uint4 wh = make_uint4(pack2(hi[0], hi[1]), pack2(hi[2], hi[3]),
                                  pack2(hi[4], hi[5]), pack2(hi[6], hi[7]));
            uint4 wl = make_uint4(pack2(lo[0], lo[1]), pack2(lo[2], lo[3]),
                                  pack2(lo[4], lo[5]), pack2(lo[6], lo[7]));
            *reinterpret_cast<uint4*>(&h1hi[m * 256 + c]) = wh;
            *reinterpret_cast<uint4*>(&h1lo[m * 256 + c]) = wl;
        }
    }
    // s2/hp2: full 256-col projections, complete rows (16 subs x 16 cols)
    {
        int row = tid & 31, sub = tid >> 5;
        float p0 = 0.f, p1 = 0.f, p2 = 0.f, p3 = 0.f, p4 = 0.f;
#pragma unroll
        for (int i = 0; i < 16; ++i) {
            int c = sub * 16 + i;
            float v = CT[row * CTS + c];
            p0 = fmaf(v, Ws2[c * 3 + 0], p0);
            p1 = fmaf(v, Ws2[c * 3 + 1], p1);
            p2 = fmaf(v, Ws2[c * 3 + 2], p2);
            p3 = fmaf(v, Wh2[c * 2 + 0], p3);
            p4 = fmaf(v, Wh2[c * 2 + 1], p4);
        }
        float* pp = &part[(row * 16 + sub) * 5];
        pp[0] = p0; pp[1] = p1; pp[2] = p2; pp[3] = p3; pp[4] = p4;
    }
    __syncthreads();
    if (tid < 160) {
        int row = tid / 5, o = tid - row * 5;
        float sum = 0.f;
#pragma unroll
        for (int k = 0; k < 16; ++k) sum += part[(row * 16 + k) * 5 + o];
        if (o < 3) s2[(m0 + row) * 3 + o] = bs2[o] + sum;
        else       hp2[(m0 + row) * 2 + (o - 3)] = bh2[o - 3] + sum;
    }
}

// ==== K3: ONE BLOCK PER GRAPH — knn2 + chunked gemm2 + LDS s3/hp3 + knn3 + final ====
__global__ __launch_bounds__(1024, 1) void k3_graph(
    const float* __restrict__ s2, const float* __restrict__ hp2,
    const ushort* __restrict__ h1hi, const ushort* __restrict__ h1lo,
    const ushort* __restrict__ Wt2hi, const ushort* __restrict__ Wt2lo,
    const float* __restrict__ Wo2, const float* __restrict__ bo2,
    const float* __restrict__ Ws3, const float* __restrict__ Wh3,
    const float* __restrict__ bs3, const float* __restrict__ bh3,
    const float* __restrict__ Wo3, const float* __restrict__ bo3,
    float* __restrict__ out)
{
    __shared__ float sh5[256 * 5];       // s2/hp2 of the graph
    __shared__ float sh5b[256 * 5];      // s3/hp3 accumulator (never leaves the block)
    __shared__ float aggL[256 * 2];      // knn2 output for all 256 rows
    __shared__ float CT[32 * CTS];       // per-chunk leaky output
    __shared__ float part[32 * 16 * 5];  // projection partials / final pm
    __shared__ float hc[256];            // leaky row g*256 (for final)

    const int g = blockIdx.x, tid = threadIdx.x;
    const int lane = tid & 63, wid = tid >> 6;    // 16 waves
    const int wr = wid >> 3, wc = wid & 7;

    if (tid < 256) {
        int node = g * GN + tid;
        sh5[tid * 5 + 0] = s2[node * 3 + 0];
        sh5[tid * 5 + 1] = s2[node * 3 + 1];
        sh5[tid * 5 + 2] = s2[node * 3 + 2];
        sh5[tid * 5 + 3] = hp2[node * 2 + 0];
        sh5[tid * 5 + 4] = hp2[node * 2 + 1];
    }
    __syncthreads();
    // knn2: 16 waves x 4 rows x 4 passes = 256 rows
#pragma unroll 1
    for (int p = 0; p < 4; ++p)
        knn_rows4(sh5, p * 64 + wid * 4, p * 64 + wid * 4, lane, aggL);
    __syncthreads();

    // gemm2 + projection in 8 chunks of 32 rows
#pragma unroll 1
    for (int c = 0; c < 8; ++c) {
        const int rbase = c * 32;
        f32x4 acc[2];
        acc[0] = (f32x4){0.f, 0.f, 0.f, 0.f};
        acc[1] = (f32x4){0.f, 0.f, 0.f, 0.f};
#pragma unroll 2
        for (int kof = 0; kof < 256; kof += 32) {
            int kch = kof + (lane >> 4) * 8;
            size_t arow = (size_t)(g * GN + rbase + wr * 16 + (lane & 15)) * 256 + kch;
            bf16x8 ah = ld8(h1hi + arow), al = ld8(h1lo + arow);
            bf16x8 bhv[2], blv[2];
#pragma unroll
            for (int ni = 0; ni < 2; ++ni) {
                size_t boff = (size_t)(wc * 32 + ni * 16 + (lane & 15)) * 256 + kch;
                bhv[ni] = ld8(Wt2hi + boff); blv[ni] = ld8(Wt2lo + boff);
            }
#pragma unroll
            for (int ni = 0; ni < 2; ++ni) {
                acc[ni] = __builtin_amdgcn_mfma_f32_16x16x32_bf16(ah, bhv[ni], acc[ni], 0, 0, 0);
                acc[ni] = __builtin_amdgcn_mfma_f32_16x16x32_bf16(ah, blv[ni], acc[ni], 0, 0, 0);
                acc[ni] = __builtin_amdgcn_mfma_f32_16x16x32_bf16(al, bhv[ni], acc[ni], 0, 0, 0);
            }
        }
        // epilogue -> CT (C/D map: col=lane&15, row=(lane>>4)*4+r)
#pragma unroll
        for (int ni = 0; ni < 2; ++ni) {
            int n = wc * 32 + ni * 16 + (lane & 15);
            float w0 = Wo2[n], w1 = Wo2[256 + n], bz = bo2[n];
            int mb = wr * 16 + ((lane >> 4) << 2);
#pragma unroll
            for (int r = 0; r < 4; ++r) {
                int ml = mb + r;   // 0..31
                float v = acc[ni][r] + fmaf(aggL[(rbase + ml) * 2 + 0], w0,
                                            fmaf(aggL[(rbase + ml) * 2 + 1], w1, bz));
                CT[ml * CTS + n] = v >= 0.f ? v : 0.01f * v;
            }
        }
        __syncthreads();
        if (c == 0 && tid < 256) hc[tid] = CT[tid];   // local row 0 == graph row g*256
        // projection of this chunk's 32 rows (512 threads: 32 rows x 16 subs x 16 cols)
        if (tid < 512) {
            int row = tid & 31, sub = tid >> 5;
            float p0 = 0.f, p1 = 0.f, p2 = 0.f, p3 = 0.f, p4 = 0.f;
#pragma unroll
            for (int i = 0; i < 16; ++i) {
                int cc = sub * 16 + i;
                float v = CT[row * CTS + cc];
                p0 = fmaf(v, Ws3[cc * 3 + 0], p0);
                p1 = fmaf(v, Ws3[cc * 3 + 1], p1);
                p2 = fmaf(v, Ws3[cc * 3 + 2], p2);
                p3 = fmaf(v, Wh3[cc * 2 + 0], p3);
                p4 = fmaf(v, Wh3[cc * 2 + 1], p4);
            }
            float* pp = &part[(row * 16 + sub) * 5];
            pp[0] = p0; pp[1] = p1; pp[2] = p2; pp[3] = p3; pp[4] = p4;
        }
        __syncthreads();
        if (tid < 160) {
            int row = tid / 5, o = tid - row * 5;
            float sum = 0.f;
#pragma unroll
            for (int k = 0; k < 16; ++k) sum += part[(row * 16 + k) * 5 + o];
            sh5b[(rbase + row) * 5 + o] = (o < 3 ? bs3[o] : bh3[o - 3]) + sum;
        }
        __syncthreads();   // sh5b/part writes done; CT free for next chunk
    }

    // ---- knn3 for local row 0 (s3/hp3 in sh5b) ----
    if (tid < 64) {
        float s0 = sh5b[0], s1v = sh5b[1], s2v = sh5b[2];
        float s2row = s0 * s0 + s1v * s1v + s2v * s2v;
        unsigned key[4]; float2 hs[4];
#pragma unroll
        for (int t = 0; t < 4; ++t) {
            int j = tid + 64 * t;
            float xx = sh5b[j * 5 + 0], y = sh5b[j * 5 + 1], z = sh5b[j * 5 + 2];
            float dot = s0 * xx + s1v * y + s2v * z;
            float d2 = s2row + (xx * xx + y * y + z * z) - 2.0f * dot;
            key[t] = __float_as_uint(d2 > 0.f ? d2 : 0.f);
            hs[t] = make_float2(sh5b[j * 5 + 3], sh5b[j * 5 + 4]);
        }
        float a0, a1;
        knn_extract(key[0], key[1], key[2], key[3], hs[0], hs[1], hs[2], hs[3], tid, a0, a1);
        if (tid == 63) { aggL[0] = a0; aggL[1] = a1; }
    }
    __syncthreads();
    // ---- final 258->32 matvec on hc ----
    if (tid < 256) {
        int o = tid & 31, seg = tid >> 5;
        float p = 0.f;
#pragma unroll
        for (int i = 0; i < 32; ++i) {
            int cc = seg * 32 + i;
            p = fmaf(hc[cc], Wo3[(2 + cc) * 32 + o], p);
        }
        part[seg * 32 + o] = p;
    }
    __syncthreads();
    if (tid < 32) {
        float accf = fmaf(aggL[0], Wo3[tid], fmaf(aggL[1], Wo3[32 + tid], bo3[tid]));
#pragma unroll
        for (int k = 0; k < 8; ++k) accf += part[k * 32 + tid];
        out[g * 32 + tid] = accf;
    }
}

extern "C" void kernel_launch(void* const* d_in, const int* in_sizes, int n_in,
                              void* d_out, int out_size, void* d_ws, size_t ws_size,
                              hipStream_t stream) {
    const float* X   = (const float*)d_in[0];
    const float* Ws1 = (const float*)d_in[2];  const float* bs1 = (const float*)d_in[3];
    const float* Wh1 = (const float*)d_in[4];  const float* bh1 = (const float*)d_in[5];
    const float* Wo1 = (const float*)d_in[6];  const float* bo1 = (const float*)d_in[7];
    const float* Ws2 = (const float*)d_in[8];  const float* bs2 = (const float*)d_in[9];
    const float* Wh2 = (const float*)d_in[10]; const float* bh2 = (const float*)d_in[11];
    const float* Wo2 = (const float*)d_in[12]; const float* bo2 = (const float*)d_in[13];
    const float* Ws3 = (const float*)d_in[14]; const float* bs3 = (const float*)d_in[15];
    const float* Wh3 = (const float*)d_in[16]; const float* bh3 = (const float*)d_in[17];
    const float* Wo3 = (const float*)d_in[18]; const float* bo3 = (const float*)d_in[19];

    float* p = (float*)d_ws;
    float* s2   = p; p += NTOT * 3;
    float* hp2  = p; p += NTOT * 2;
    ushort* q = (ushort*)p;
    ushort* h1hi = q; q += (size_t)NTOT * 256;
    ushort* h1lo = q; q += (size_t)NTOT * 256;
    ushort* Wt2hi = q; q += 256 * 256;
    ushort* Wt2lo = q; q += 256 * 256;

    k2_fused<<<384, 512, 0, stream>>>(X, Ws1, bs1, Wh1, bh1, Wo1, bo1,
                                      Ws2, Wh2, bs2, bh2, Wo2,
                                      Wt2hi, Wt2lo, h1hi, h1lo, s2, hp2);
    k3_graph<<<NGRAPH, 1024, 0, stream>>>(s2, hp2, h1hi, h1lo, Wt2hi, Wt2lo,
                                          Wo2, bo2, Ws3, Wh3, bs3, bh3,
                                          Wo3, bo3, (float*)d_out);
}

// Round 18
// 69.616 us; speedup vs baseline: 4.7195x; 4.7195x over previous
//
#include <hip/hip_runtime.h>
#include <hip/hip_bf16.h>

// GravNet: 32 graphs x 256 nodes, IN=64, HID=256, OUT=32, K=20, SPACE=3, PROP=2
// 3-launch pipeline, zero cross-block sync (handoffs = plain stores across kernel bounds):
//  K2 (384 blk x 512 thr): blocks 0..255: BM=32 — in-block sh1 + kNN own 32 rows +
//     gemm1 (A=X split->LDS swz; B=Wo1 split IN REGISTERS) + h1 planes + complete s2/hp2.
//     blocks 256..383: rider = Wo2 -> Wt2 hi/lo split.
//  K3 (256 blk x 512 thr): BM=32 — knn2 + gemm2 K=256 + h2c + s3/hp3.
//  K4 (32 blk x 256 thr): per-graph kNN of row g*256 + final matvec.
// [R18: byte-for-byte revert to R14 — best verified (69.1us, passed incl. post-timing
//  determinism). R15 (fence fold, 78.9), R16 (1-blk/graph, 328), R17 (fragment layout,
//  post-timing divergence) all rejected.]
// GEMM x-part: split-bf16 MFMA (hi/lo, 3 products) == fp32 precision.

#define NGRAPH 32
#define GN 256
#define NTOT (NGRAPH*GN) // 8192
#define KNN 20
#define CTS 257          // CT leading dim (floats): 257%32==1 -> conflict-free columns

typedef __attribute__((ext_vector_type(8))) short bf16x8;
typedef __attribute__((ext_vector_type(4))) float f32x4;

__device__ __forceinline__ ushort f2bf(float x) {
    union { float f; unsigned u; } a; a.f = x;
    unsigned r = a.u + 0x7FFFu + ((a.u >> 16) & 1u);   // RNE
    return (ushort)(r >> 16);
}
__device__ __forceinline__ float bf2f(ushort h) {
    union { unsigned u; float f; } b; b.u = ((unsigned)h) << 16;
    return b.f;
}
__device__ __forceinline__ bf16x8 ld8(const ushort* p) {
    return *reinterpret_cast<const bf16x8*>(p);
}
__device__ __forceinline__ unsigned pack2(ushort a, ushort b) {
    return (unsigned)a | ((unsigned)b << 16);
}

// ---- DPP primitives (VALU-only) ----
#define DPP_MIN(v, ctrl, rmask) { \
    unsigned _t = (unsigned)__builtin_amdgcn_update_dpp((int)(v), (int)(v), ctrl, rmask, 0xf, false); \
    (v) = _t < (v) ? _t : (v); }
#define DPP_ADD(v, ctrl, rmask) { \
    float _t = __int_as_float(__builtin_amdgcn_update_dpp(0, __float_as_int(v), ctrl, rmask, 0xf, true)); \
    (v) += _t; }
__device__ __forceinline__ unsigned wave_min_u32(unsigned v) {
    DPP_MIN(v, 0x111, 0xf)
    DPP_MIN(v, 0x112, 0xf)
    DPP_MIN(v, 0x114, 0xf)
    DPP_MIN(v, 0x118, 0xf)
    DPP_MIN(v, 0x142, 0xa)
    DPP_MIN(v, 0x143, 0xc)
    return (unsigned)__builtin_amdgcn_readlane((int)v, 63);
}
__device__ __forceinline__ float wave_sum_f32(float v) {
    DPP_ADD(v, 0x111, 0xf)
    DPP_ADD(v, 0x112, 0xf)
    DPP_ADD(v, 0x114, 0xf)
    DPP_ADD(v, 0x118, 0xf)
    DPP_ADD(v, 0x142, 0xa)
    DPP_ADD(v, 0x143, 0xc)
    return __int_as_float(__builtin_amdgcn_readlane(__float_as_int(v), 63));
}

// ---- serial kNN extraction (K4 only) ----
__device__ __forceinline__ void knn_extract(
    unsigned ua, unsigned ub, unsigned uc, unsigned ud,
    float2 hA, float2 hB, float2 hC, float2 hD,
    int lane, float& out0, float& out1)
{
    float acc0 = 0.f, acc1 = 0.f;
#pragma unroll 1
    for (int it = 0; it < KNN; ++it) {
        unsigned m1 = ua < ub ? ua : ub;
        unsigned m2 = uc < ud ? uc : ud;
        unsigned bv = m1 < m2 ? m1 : m2;
        unsigned gv = wave_min_u32(bv);
        float d2 = __uint_as_float(gv);
        float w = __expf(-10.0f * d2);
        unsigned long long mask = __ballot(bv == gv);
        int wl = __ffsll(mask) - 1;
        if (lane == wl) {
            float h0, h1;
            if (ua == gv)      { h0 = hA.x; h1 = hA.y; ua = 0xFFFFFFFFu; }
            else if (ub == gv) { h0 = hB.x; h1 = hB.y; ub = 0xFFFFFFFFu; }
            else if (uc == gv) { h0 = hC.x; h1 = hC.y; uc = 0xFFFFFFFFu; }
            else               { h0 = hD.x; h1 = hD.y; ud = 0xFFFFFFFFu; }
            acc0 = fmaf(w, h0, acc0);
            acc1 = fmaf(w, h1, acc1);
        }
    }
    out0 = wave_sum_f32(acc0);
    out1 = wave_sum_f32(acc1);
}

// ---- 4 kNN rows per wave (ILP-interleaved chains); sh5 = [256][5] LDS; out -> aggL LDS --
__device__ __forceinline__ void knn_rows4(
    const float* sh5, int srow, int orow, int lane, float* __restrict__ aggL)
{
    float sjx[4], sjy[4], sjz[4], s2j[4];
    float2 hs[4];
#pragma unroll
    for (int t = 0; t < 4; ++t) {
        int j = lane + 64 * t;
        float x = sh5[j * 5 + 0], y = sh5[j * 5 + 1], z = sh5[j * 5 + 2];
        sjx[t] = x; sjy[t] = y; sjz[t] = z;
        s2j[t] = x * x + y * y + z * z;
        hs[t] = make_float2(sh5[j * 5 + 3], sh5[j * 5 + 4]);
    }
    unsigned key[4][4];
    float acc0[4], acc1[4];
#pragma unroll
    for (int r = 0; r < 4; ++r) {
        int rl = srow + r;
        float s0 = sh5[rl * 5 + 0], s1v = sh5[rl * 5 + 1], s2v = sh5[rl * 5 + 2];
        float s2row = s0 * s0 + s1v * s1v + s2v * s2v;
#pragma unroll
        for (int t = 0; t < 4; ++t) {
            float dot = s0 * sjx[t] + s1v * sjy[t] + s2v * sjz[t];
            float d2 = s2row + s2j[t] - 2.0f * dot;
            key[r][t] = __float_as_uint(d2 > 0.f ? d2 : 0.f);
        }
        acc0[r] = 0.f; acc1[r] = 0.f;
    }
#pragma unroll 1
    for (int it = 0; it < KNN; ++it) {
        unsigned bv[4], gv[4];
#pragma unroll
        for (int r = 0; r < 4; ++r) {
            unsigned m1 = key[r][0] < key[r][1] ? key[r][0] : key[r][1];
            unsigned m2 = key[r][2] < key[r][3] ? key[r][2] : key[r][3];
            bv[r] = m1 < m2 ? m1 : m2;
            gv[r] = bv[r];
        }
#define KSTAGE(ctrl, rmask) { \
        DPP_MIN(gv[0], ctrl, rmask) DPP_MIN(gv[1], ctrl, rmask) \
        DPP_MIN(gv[2], ctrl, rmask) DPP_MIN(gv[3], ctrl, rmask) }
        KSTAGE(0x111, 0xf) KSTAGE(0x112, 0xf) KSTAGE(0x114, 0xf)
        KSTAGE(0x118, 0xf) KSTAGE(0x142, 0xa) KSTAGE(0x143, 0xc)
#undef KSTAGE
#pragma unroll
        for (int r = 0; r < 4; ++r) {
            unsigned g = (unsigned)__builtin_amdgcn_readlane((int)gv[r], 63);
            float w = __expf(-10.0f * __uint_as_float(g));
            unsigned long long mask = __ballot(bv[r] == g);
            int wl = __ffsll(mask) - 1;
            if (lane == wl) {
                float h0, h1;
                if (key[r][0] == g)      { h0 = hs[0].x; h1 = hs[0].y; key[r][0] = 0xFFFFFFFFu; }
                else if (key[r][1] == g) { h0 = hs[1].x; h1 = hs[1].y; key[r][1] = 0xFFFFFFFFu; }
                else if (key[r][2] == g) { h0 = hs[2].x; h1 = hs[2].y; key[r][2] = 0xFFFFFFFFu; }
                else                     { h0 = hs[3].x; h1 = hs[3].y; key[r][3] = 0xFFFFFFFFu; }
                acc0[r] = fmaf(w, h0, acc0[r]);
                acc1[r] = fmaf(w, h1, acc1[r]);
            }
        }
    }
#define SSTAGE(ctrl, rmask) { \
    DPP_ADD(acc0[0], ctrl, rmask) DPP_ADD(acc1[0], ctrl, rmask) \
    DPP_ADD(acc0[1], ctrl, rmask) DPP_ADD(acc1[1], ctrl, rmask) \
    DPP_ADD(acc0[2], ctrl, rmask) DPP_ADD(acc1[2], ctrl, rmask) \
    DPP_ADD(acc0[3], ctrl, rmask) DPP_ADD(acc1[3], ctrl, rmask) }
    SSTAGE(0x111, 0xf) SSTAGE(0x112, 0xf) SSTAGE(0x114, 0xf)
    SSTAGE(0x118, 0xf) SSTAGE(0x142, 0xa) SSTAGE(0x143, 0xc)
#undef SSTAGE
    if (lane == 63) {
#pragma unroll
        for (int r = 0; r < 4; ++r) {
            aggL[(orow + r) * 2 + 0] = acc0[r];
            aggL[(orow + r) * 2 + 1] = acc1[r];
        }
    }
}

// ========== K2: BM=32 — sh1 + knn1 + gemm1 (B in regs) + h1 + s2/hp2 | Wt2 rider ==========
__global__ __launch_bounds__(512) void k2_fused(
    const float* __restrict__ X,
    const float* __restrict__ Ws1, const float* __restrict__ bs1,
    const float* __restrict__ Wh1, const float* __restrict__ bh1,
    const float* __restrict__ Wo1, const float* __restrict__ bo1,
    const float* __restrict__ Ws2, const float* __restrict__ Wh2,
    const float* __restrict__ bs2, const float* __restrict__ bh2,
    const float* __restrict__ Wo2,
    ushort* __restrict__ Wt2hi, ushort* __restrict__ Wt2lo,
    ushort* __restrict__ h1hi, ushort* __restrict__ h1lo,
    float* __restrict__ s2, float* __restrict__ hp2)
{
    const int x = blockIdx.x, tid = threadIdx.x;
    if (x >= 256) {                        // ---- rider: Wo2[2+c][n] -> Wt2[n][c] hi/lo
        int t = (x - 256) * 512 + tid;     // 0..65535
        int n = t >> 8, c = t & 255;
        float v = Wo2[(size_t)(2 + c) * 256 + n];
        ushort hi = f2bf(v);
        Wt2hi[n * 256 + c] = hi;
        Wt2lo[n * 256 + c] = f2bf(v - bf2f(hi));
        return;
    }
    __shared__ float sh5[256 * 5];
    __shared__ float aggL[32 * 2];
    __shared__ ushort Ahi[32 * 64];
    __shared__ ushort Alo[32 * 64];
    __shared__ float CT[32 * CTS];
    __shared__ float part[32 * 16 * 5];    // total ~56.7 KB -> 2 blk/CU

    const int lane = tid & 63, wid = tid >> 6;
    const int g = x >> 3, m0 = x * 32, lr0 = (x & 7) * 32;

    // B fragments (Wo1) straight to REGISTERS: wave owns n-range wid*32..+31.
    bf16x8 bh[2][2], bl[2][2];   // [kof/32][ni]
    {
        int nb = wid * 32 + (lane & 15);
        int k0 = (lane >> 4) * 8;
#pragma unroll
        for (int kk = 0; kk < 2; ++kk)
#pragma unroll
            for (int ni = 0; ni < 2; ++ni) {
                union { bf16x8 v; ushort u[8]; } H, L;
#pragma unroll
                for (int j = 0; j < 8; ++j) {
                    float v = Wo1[(size_t)(2 + kk * 32 + k0 + j) * 256 + nb + ni * 16];
                    ushort hi = f2bf(v);
                    H.u[j] = hi;
                    L.u[j] = f2bf(v - bf2f(hi));
                }
                bh[kk][ni] = H.v; bl[kk][ni] = L.v;
            }
    }
    // sh1: project all 256 nodes of graph g (redundant x8 across sibling blocks)
    if (tid < 256) {
        const float* xr = X + ((size_t)g * GN + tid) * 64;
        float a0 = 0.f, a1 = 0.f, a2 = 0.f, a3 = 0.f, a4 = 0.f;
#pragma unroll 4
        for (int c0 = 0; c0 < 64; c0 += 4) {
            float4 v = *reinterpret_cast<const float4*>(&xr[c0]);
            float xv[4] = {v.x, v.y, v.z, v.w};
#pragma unroll
            for (int j = 0; j < 4; ++j) {
                int c = c0 + j;
                a0 = fmaf(xv[j], Ws1[c * 3 + 0], a0);
                a1 = fmaf(xv[j], Ws1[c * 3 + 1], a1);
                a2 = fmaf(xv[j], Ws1[c * 3 + 2], a2);
                a3 = fmaf(xv[j], Wh1[c * 2 + 0], a3);
                a4 = fmaf(xv[j], Wh1[c * 2 + 1], a4);
            }
        }
        sh5[tid * 5 + 0] = a0 + bs1[0];
        sh5[tid * 5 + 1] = a1 + bs1[1];
        sh5[tid * 5 + 2] = a2 + bs1[2];
        sh5[tid * 5 + 3] = a3 + bh1[0];
        sh5[tid * 5 + 4] = a4 + bh1[1];
    }
    // A-split: X rows m0..m0+31 -> Ahi/Alo (XOR-swizzled), 1 float4/thread
    {
        int row = tid >> 4, c4 = (tid & 15) * 4;
        float4 v = *reinterpret_cast<const float4*>(&X[(size_t)(m0 + row) * 64 + c4]);
        int idx = (row * 64 + c4) ^ ((row & 7) << 3);
        ushort4 hi, lo;
        hi.x = f2bf(v.x); lo.x = f2bf(v.x - bf2f(hi.x));
        hi.y = f2bf(v.y); lo.y = f2bf(v.y - bf2f(hi.y));
        hi.z = f2bf(v.z); lo.z = f2bf(v.z - bf2f(hi.z));
        hi.w = f2bf(v.w); lo.w = f2bf(v.w - bf2f(hi.w));
        *reinterpret_cast<ushort4*>(&Ahi[idx]) = hi;
        *reinterpret_cast<ushort4*>(&Alo[idx]) = lo;
    }
    __syncthreads();

    knn_rows4(sh5, lr0 + wid * 4, wid * 4, lane, aggL);

    // gemm1: BM=32, wave-local 32 cols, K=64; acc[2][2]
    f32x4 acc[2][2];
#pragma unroll
    for (int mi = 0; mi < 2; ++mi)
#pragma unroll
        for (int ni = 0; ni < 2; ++ni)
            acc[mi][ni] = (f32x4){0.f, 0.f, 0.f, 0.f};
#pragma unroll
    for (int kk = 0; kk < 2; ++kk) {
        int kch = kk * 32 + (lane >> 4) * 8;
        bf16x8 ah[2], al[2];
#pragma unroll
        for (int mi = 0; mi < 2; ++mi) {
            int r = mi * 16 + (lane & 15);
            int idx = (r * 64 + kch) ^ ((r & 7) << 3);
            ah[mi] = ld8(&Ahi[idx]); al[mi] = ld8(&Alo[idx]);
        }
#pragma unroll
        for (int mi = 0; mi < 2; ++mi)
#pragma unroll
            for (int ni = 0; ni < 2; ++ni) {
                acc[mi][ni] = __builtin_amdgcn_mfma_f32_16x16x32_bf16(ah[mi], bh[kk][ni], acc[mi][ni], 0, 0, 0);
                acc[mi][ni] = __builtin_amdgcn_mfma_f32_16x16x32_bf16(ah[mi], bl[kk][ni], acc[mi][ni], 0, 0, 0);
                acc[mi][ni] = __builtin_amdgcn_mfma_f32_16x16x32_bf16(al[mi], bh[kk][ni], acc[mi][ni], 0, 0, 0);
            }
    }
    __syncthreads();   // aggL complete before epilogue

    // epilogue: + agg@Wa + bias, leaky -> CT (C/D map: col=lane&15, row=(lane>>4)*4+r)
#pragma unroll
    for (int ni = 0; ni < 2; ++ni) {
        int n = wid * 32 + ni * 16 + (lane & 15);
        float w0 = Wo1[n], w1 = Wo1[256 + n], bz = bo1[n];
#pragma unroll
        for (int mi = 0; mi < 2; ++mi) {
            int mb = mi * 16 + ((lane >> 4) << 2);
#pragma unroll
            for (int r = 0; r < 4; ++r) {
                int ml = mb + r;
                float v = acc[mi][ni][r] + fmaf(aggL[ml * 2 + 0], w0, fmaf(aggL[ml * 2 + 1], w1, bz));
                CT[ml * CTS + n] = v >= 0.f ? v : 0.01f * v;
            }
        }
    }
    __syncthreads();

    // h1 planes from CT (coalesced packed stores): 512 thr x 16 cols
    {
        int row = tid >> 4, cb = (tid & 15) * 16;
        size_t m = (size_t)(m0 + row);
#pragma unroll
        for (int j = 0; j < 2; ++j) {
            int c = cb + j * 8;
            ushort hi[8], lo[8];
#pragma unroll
            for (int t = 0; t < 8; ++t) {
                float v = CT[row * CTS + c + t];
                hi[t] = f2bf(v);
                lo[t] = f2bf(v - bf2f(hi[t]));
            }
            uint4 wh = make_uint4(pack2(hi[0], hi[1]), pack2(hi[2], hi[3]),
                                  pack2(hi[4], hi[5]), pack2(hi[6], hi[7]));
            uint4 wl = make_uint4(pack2(lo[0], lo[1]), pack2(lo[2], lo[3]),
                                  pack2(lo[4], lo[5]), pack2(lo[6], lo[7]));
            *reinterpret_cast<uint4*>(&h1hi[m * 256 + c]) = wh;
            *reinterpret_cast<uint4*>(&h1lo[m * 256 + c]) = wl;
        }
    }
    // s2/hp2: full 256-col projections, complete rows (16 subs x 16 cols)
    {
        int row = tid & 31, sub = tid >> 5;
        float p0 = 0.f, p1 = 0.f, p2 = 0.f, p3 = 0.f, p4 = 0.f;
#pragma unroll
        for (int i = 0; i < 16; ++i) {
            int c = sub * 16 + i;
            float v = CT[row * CTS + c];
            p0 = fmaf(v, Ws2[c * 3 + 0], p0);
            p1 = fmaf(v, Ws2[c * 3 + 1], p1);
            p2 = fmaf(v, Ws2[c * 3 + 2], p2);
            p3 = fmaf(v, Wh2[c * 2 + 0], p3);
            p4 = fmaf(v, Wh2[c * 2 + 1], p4);
        }
        float* pp = &part[(row * 16 + sub) * 5];
        pp[0] = p0; pp[1] = p1; pp[2] = p2; pp[3] = p3; pp[4] = p4;
    }
    __syncthreads();
    if (tid < 160) {
        int row = tid / 5, o = tid - row * 5;
        float sum = 0.f;
#pragma unroll
        for (int k = 0; k < 16; ++k) sum += part[(row * 16 + k) * 5 + o];
        if (o < 3) s2[(m0 + row) * 3 + o] = bs2[o] + sum;
        else       hp2[(m0 + row) * 2 + (o - 3)] = bh2[o - 3] + sum;
    }
}

// ======== K3: knn2 + gemm2 (K=256, BN=256), BM=32, 256 blocks + h2c + s3/hp3 ========
__global__ __launch_bounds__(512) void k3_fused(
    const float* __restrict__ s2, const float* __restrict__ hp2,
    const ushort* __restrict__ h1hi, const ushort* __restrict__ h1lo,
    const ushort* __restrict__ Wt2hi, const ushort* __restrict__ Wt2lo,
    const float* __restrict__ Wo2, const float* __restrict__ bo2,
    const float* __restrict__ Ws3, const float* __restrict__ Wh3,
    const float* __restrict__ bs3, const float* __restrict__ bh3,
    float* __restrict__ h2c, float* __restrict__ s3, float* __restrict__ hp3)
{
    __shared__ float sh5[256 * 5];
    __shared__ float aggL[32 * 2];
    __shared__ float CT[32 * CTS];
    __shared__ float part[32 * 16 * 5];

    const int x = blockIdx.x, tid = threadIdx.x;
    const int lane = tid & 63, wid = tid >> 6;
    const int g = x >> 3, m0 = x * 32, lr0 = (x & 7) * 32;

    if (tid < 256) {
        int node = g * GN + tid;
        sh5[tid * 5 + 0] = s2[node * 3 + 0];
        sh5[tid * 5 + 1] = s2[node * 3 + 1];
        sh5[tid * 5 + 2] = s2[node * 3 + 2];
        sh5[tid * 5 + 3] = hp2[node * 2 + 0];
        sh5[tid * 5 + 4] = hp2[node * 2 + 1];
    }
    __syncthreads();
    knn_rows4(sh5, lr0 + wid * 4, wid * 4, lane, aggL);
    __syncthreads();

    // gemm2: BM=32, BN=256, K=256; 8 waves 1m x 8n, each 32x32
    f32x4 acc[2][2];
#pragma unroll
    for (int mi = 0; mi < 2; ++mi)
#pragma unroll
        for (int ni = 0; ni < 2; ++ni)
            acc[mi][ni] = (f32x4){0.f, 0.f, 0.f, 0.f};
#pragma unroll 2
    for (int kof = 0; kof < 256; kof += 32) {
        int kch = kof + (lane >> 4) * 8;
        bf16x8 ah[2], al[2], bh[2], bl[2];
#pragma unroll
        for (int mi = 0; mi < 2; ++mi) {
            size_t off = (size_t)(m0 + mi * 16 + (lane & 15)) * 256 + kch;
            ah[mi] = ld8(h1hi + off); al[mi] = ld8(h1lo + off);
        }
#pragma unroll
        for (int ni = 0; ni < 2; ++ni) {
            size_t off = (size_t)(wid * 32 + ni * 16 + (lane & 15)) * 256 + kch;
            bh[ni] = ld8(Wt2hi + off); bl[ni] = ld8(Wt2lo + off);
        }
#pragma unroll
        for (int mi = 0; mi < 2; ++mi)
#pragma unroll
            for (int ni = 0; ni < 2; ++ni) {
                acc[mi][ni] = __builtin_amdgcn_mfma_f32_16x16x32_bf16(ah[mi], bh[ni], acc[mi][ni], 0, 0, 0);
                acc[mi][ni] = __builtin_amdgcn_mfma_f32_16x16x32_bf16(ah[mi], bl[ni], acc[mi][ni], 0, 0, 0);
                acc[mi][ni] = __builtin_amdgcn_mfma_f32_16x16x32_bf16(al[mi], bh[ni], acc[mi][ni], 0, 0, 0);
            }
    }

    // epilogue: + agg@Wa + bias, leaky -> CT (C/D map: col=lane&15, row=(lane>>4)*4+r)
#pragma unroll
    for (int ni = 0; ni < 2; ++ni) {
        int n = wid * 32 + ni * 16 + (lane & 15);
        float w0 = Wo2[n], w1 = Wo2[256 + n], bz = bo2[n];
#pragma unroll
        for (int mi = 0; mi < 2; ++mi) {
            int mb = mi * 16 + ((lane >> 4) << 2);
#pragma unroll
            for (int r = 0; r < 4; ++r) {
                int ml = mb + r;
                float v = acc[mi][ni][r] + fmaf(aggL[ml * 2 + 0], w0, fmaf(aggL[ml * 2 + 1], w1, bz));
                CT[ml * CTS + n] = v >= 0.f ? v : 0.01f * v;
            }
        }
    }
    __syncthreads();

    // h2c: block x=8g holds global row g*256 at ml=0
    if ((x & 7) == 0 && tid < 256) h2c[g * 256 + tid] = CT[tid];

    // s3/hp3: full 256-col projections, complete rows (16 subs x 16 cols)
    {
        int row = tid & 31, sub = tid >> 5;
        float p0 = 0.f, p1 = 0.f, p2 = 0.f, p3 = 0.f, p4 = 0.f;
#pragma unroll
        for (int i = 0; i < 16; ++i) {
            int c = sub * 16 + i;
            float v = CT[row * CTS + c];
            p0 = fmaf(v, Ws3[c * 3 + 0], p0);
            p1 = fmaf(v, Ws3[c * 3 + 1], p1);
            p2 = fmaf(v, Ws3[c * 3 + 2], p2);
            p3 = fmaf(v, Wh3[c * 2 + 0], p3);
            p4 = fmaf(v, Wh3[c * 2 + 1], p4);
        }
        float* pp = &part[(row * 16 + sub) * 5];
        pp[0] = p0; pp[1] = p1; pp[2] = p2; pp[3] = p3; pp[4] = p4;
    }
    __syncthreads();
    if (tid < 160) {
        int row = tid / 5, o = tid - row * 5;
        float sum = 0.f;
#pragma unroll
        for (int k = 0; k < 16; ++k) sum += part[(row * 16 + k) * 5 + o];
        if (o < 3) s3[(m0 + row) * 3 + o] = bs3[o] + sum;
        else       hp3[(m0 + row) * 2 + (o - 3)] = bh3[o - 3] + sum;
    }
}

// ================= K4: per-graph kNN of row g*256 + final matvec =================
__global__ __launch_bounds__(256) void knn3_final(
    const float* __restrict__ s, const float* __restrict__ h,
    const float* __restrict__ h2c,
    const float* __restrict__ Wo, const float* __restrict__ bo,
    float* __restrict__ out)
{
    __shared__ float aggL[2];
    __shared__ float pm[8][32];
    int g = blockIdx.x, tid = threadIdx.x;
    if (tid < 64) {
        int lane = tid;
        int base = g * GN, row = g * GN;
        float s0 = s[row * 3 + 0], s1v = s[row * 3 + 1], s2v = s[row * 3 + 2];
        float s2row = s0 * s0 + s1v * s1v + s2v * s2v;
        unsigned key[4]; float2 hs[4];
#pragma unroll
        for (int t = 0; t < 4; ++t) {
            int j = base + lane + 64 * t;
            float xx = s[j * 3 + 0], y = s[j * 3 + 1], z = s[j * 3 + 2];
            float dot = s0 * xx + s1v * y + s2v * z;
            float d2 = s2row + (xx * xx + y * y + z * z) - 2.0f * dot;
            key[t] = __float_as_uint(d2 > 0.f ? d2 : 0.f);
            hs[t] = *reinterpret_cast<const float2*>(&h[(size_t)j * 2]);
        }
        float a0, a1;
        knn_extract(key[0], key[1], key[2], key[3], hs[0], hs[1], hs[2], hs[3], lane, a0, a1);
        if (lane == 63) { aggL[0] = a0; aggL[1] = a1; }
    }
    __syncthreads();
    int o = tid & 31, seg = tid >> 5;
    const float* xr = h2c + g * 256;
    float p = 0.f;
#pragma unroll
    for (int i = 0; i < 32; ++i) {
        int c = seg * 32 + i;
        p = fmaf(xr[c], Wo[(2 + c) * 32 + o], p);
    }
    pm[seg][o] = p;
    __syncthreads();
    if (tid < 32) {
        float acc = fmaf(aggL[0], Wo[o], fmaf(aggL[1], Wo[32 + o], bo[o]));
#pragma unroll
        for (int k = 0; k < 8; ++k) acc += pm[k][o];
        out[g * 32 + o] = acc;
    }
}

extern "C" void kernel_launch(void* const* d_in, const int* in_sizes, int n_in,
                              void* d_out, int out_size, void* d_ws, size_t ws_size,
                              hipStream_t stream) {
    const float* X   = (const float*)d_in[0];
    const float* Ws1 = (const float*)d_in[2];  const float* bs1 = (const float*)d_in[3];
    const float* Wh1 = (const float*)d_in[4];  const float* bh1 = (const float*)d_in[5];
    const float* Wo1 = (const float*)d_in[6];  const float* bo1 = (const float*)d_in[7];
    const float* Ws2 = (const float*)d_in[8];  const float* bs2 = (const float*)d_in[9];
    const float* Wh2 = (const float*)d_in[10]; const float* bh2 = (const float*)d_in[11];
    const float* Wo2 = (const float*)d_in[12]; const float* bo2 = (const float*)d_in[13];
    const float* Ws3 = (const float*)d_in[14]; const float* bs3 = (const float*)d_in[15];
    const float* Wh3 = (const float*)d_in[16]; const float* bh3 = (const float*)d_in[17];
    const float* Wo3 = (const float*)d_in[18]; const float* bo3 = (const float*)d_in[19];

    float* p = (float*)d_ws;
    float* s2   = p; p += NTOT * 3;
    float* hp2  = p; p += NTOT * 2;
    float* s3   = p; p += NTOT * 3;
    float* hp3  = p; p += NTOT * 2;
    float* h2c  = p; p += 32 * 256;
    ushort* q = (ushort*)p;
    ushort* h1hi = q; q += (size_t)NTOT * 256;
    ushort* h1lo = q; q += (size_t)NTOT * 256;
    ushort* Wt2hi = q; q += 256 * 256;
    ushort* Wt2lo = q; q += 256 * 256;

    k2_fused<<<384, 512, 0, stream>>>(X, Ws1, bs1, Wh1, bh1, Wo1, bo1,
                                      Ws2, Wh2, bs2, bh2, Wo2,
                                      Wt2hi, Wt2lo, h1hi, h1lo, s2, hp2);
    k3_fused<<<256, 512, 0, stream>>>(s2, hp2, h1hi, h1lo, Wt2hi, Wt2lo,
                                      Wo2, bo2, Ws3, Wh3, bs3, bh3,
                                      h2c, s3, hp3);
    knn3_final<<<NGRAPH, 256, 0, stream>>>(s3, hp3, h2c, Wo3, bo3, (float*)d_out);
}